// Round 3
// baseline (382.208 us; speedup 1.0000x reference)
//
#include <hip/hip_runtime.h>
#include <stdint.h>

// DreamGraphReasoner on MI355X (gfx950)
// x layout: (N, B, D) row-major, row r = n*B + b  (== input (G,L,B,D) flat order)
// Sparse attention: node n=(g,l) attends to {(g',l): g'!=g} U {(g,l+1) if l<63}
// Fusion: attended@Whop = attn@(V@Whop)  =>  QKV GEMM emits Q|K|VW_h directly,
// attn kernel mixes VW rows and applies residual+relu epilogue. No hop GEMM.

typedef __bf16 bf16;
typedef __bf16 bf16x8 __attribute__((ext_vector_type(8)));
typedef __bf16 bf16x4 __attribute__((ext_vector_type(4)));
typedef float  f32x4  __attribute__((ext_vector_type(4)));

__device__ __forceinline__ void gload_lds16(const void* g, void* l) {
  __builtin_amdgcn_global_load_lds(
      (__attribute__((address_space(1))) void*)(size_t)(g),
      (__attribute__((address_space(3))) void*)(l), 16, 0, 0);
}

// ---------------- weight prep (coalesced reads; scattered writes L2-combine) --
// ranges: [0,524288) WtQK | [..+524288) W1t | [..+524288) W2t | +1024 bcat | +1536 bvw
__global__ void prep_weights(const float* __restrict__ Wq, const float* __restrict__ Wk,
                             const float* __restrict__ bq, const float* __restrict__ bk,
                             const float* __restrict__ bv, const float* __restrict__ Whop,
                             const float* __restrict__ W1, const float* __restrict__ W2,
                             bf16* __restrict__ WtQK, float* __restrict__ bcat,
                             float* __restrict__ bvw,
                             float* __restrict__ W1t, float* __restrict__ W2t) {
  int t = blockIdx.x * 256 + threadIdx.x;
  if (t < 524288) {                        // WtQK[sel*512+c][k] = W[k][c]
    int sel = t >> 18, k = (t >> 9) & 511, c = t & 511;
    const float* W = sel ? Wk : Wq;
    WtQK[(size_t)(sel * 512 + c) * 512 + k] = (bf16)W[k * 512 + c];
  } else if (t < 2 * 524288) {             // W1t[o][d] = W1[d][o]
    int u = t - 524288;
    int d = u >> 10, o = u & 1023;
    W1t[(size_t)o * 512 + d] = W1[d * 1024 + o];
  } else if (t < 3 * 524288) {             // W2t[o][d] = W2[d][o]
    int u = t - 2 * 524288;
    int d = u >> 9, o = u & 511;
    W2t[(size_t)o * 1024 + d] = W2[d * 512 + o];
  } else if (t < 3 * 524288 + 1024) {
    int u = t - 3 * 524288;
    bcat[u] = (u < 512) ? bq[u] : bk[u - 512];
  } else if (t < 3 * 524288 + 1024 + 1536) { // bvw[h][c] = sum_k bv[k]*Whop[h][k][c]
    int u = t - (3 * 524288 + 1024);
    int h = u >> 9, c = u & 511;
    float s = 0.f;
    for (int k = 0; k < 512; ++k) s += bv[k] * Whop[h * 262144 + k * 512 + c];
    bvw[u] = s;
  }
}

// ---------------- Wvw[h] = Wv @ Whop[h] (f32 accum -> bf16, transposed) -------
// WvwT[h][c][k] = sum_d Wv[k][d] * Whop[h][d][c];  grid 192 = 3 hops x 64 c-tiles
__global__ __launch_bounds__(256)
void wvw_kernel(const float* __restrict__ Wv, const float* __restrict__ Whop,
                bf16* __restrict__ WvwT) {
  int blk = blockIdx.x;
  int h = blk >> 6;
  int c0 = (blk & 63) * 8;
  int k = threadIdx.x;
  const float* whb = Whop + h * 262144 + c0;   // [d*512 + c]
  const float* wv0 = Wv + (size_t)k * 512;
  const float* wv1 = Wv + (size_t)(k + 256) * 512;
  float a0[8] = {0, 0, 0, 0, 0, 0, 0, 0};
  float a1[8] = {0, 0, 0, 0, 0, 0, 0, 0};
  for (int d = 0; d < 512; ++d) {
    float v0 = wv0[d], v1 = wv1[d];
#pragma unroll
    for (int c = 0; c < 8; ++c) {
      float w = whb[d * 512 + c];   // uniform across threads -> scalar load
      a0[c] += w * v0;
      a1[c] += w * v1;
    }
  }
  bf16* outb = WvwT + h * 262144;
#pragma unroll
  for (int c = 0; c < 8; ++c) {
    outb[(size_t)(c0 + c) * 512 + k]       = (bf16)a0[c];
    outb[(size_t)(c0 + c) * 512 + k + 256] = (bf16)a1[c];
  }
}

// ---------------- node embeddings: x = mean(what,action,result) --------------
__global__ void nodes_kernel(const float4* __restrict__ w, const float4* __restrict__ a,
                             const float4* __restrict__ r, float4* __restrict__ x,
                             bf16x4* __restrict__ xb) {
  size_t i = (size_t)blockIdx.x * 256 + threadIdx.x;
#pragma unroll
  for (int it = 0; it < 4; ++it, i += 524288) {
    float4 vw = w[i], va = a[i], vr = r[i];
    float4 v;
    v.x = (vw.x + va.x + vr.x) * (1.f / 3.f);
    v.y = (vw.y + va.y + vr.y) * (1.f / 3.f);
    v.z = (vw.z + va.z + vr.z) * (1.f / 3.f);
    v.w = (vw.w + va.w + vr.w) * (1.f / 3.f);
    x[i] = v;
    bf16x4 bv4;
    bv4[0] = (bf16)v.x; bv4[1] = (bf16)v.y; bv4[2] = (bf16)v.z; bv4[3] = (bf16)v.w;
    xb[i] = bv4;
  }
}

// ---------------- bf16 MFMA GEMM: QKW = A(16384x512) @ [WqT|WkT|WvwT]^T + bias
// 128x128 tile, BK=32, global_load_lds w16, XOR-swizzled LDS k-chunks (both sides)
__global__ __launch_bounds__(256)
void gemm_qkw(const bf16* __restrict__ A, const bf16* __restrict__ BtQK,
              const bf16* __restrict__ BtVW, const float* __restrict__ biasQK,
              const float* __restrict__ biasVW, bf16* __restrict__ out) {
  constexpr int BK = 32;
  __shared__ __align__(16) bf16 As[128 * BK];
  __shared__ __align__(16) bf16 Bs[128 * BK];
  const int tid = threadIdx.x;
  const int wave = tid >> 6, lane = tid & 63;
  const int wr = wave >> 1, wc = wave & 1;
  const int m0 = blockIdx.x * 128;
  const int n0 = blockIdx.y * 128;
  // N-section select (uniform per block): cols >=1024 come from per-hop WvwT
  const bf16* Bt = (n0 < 1024) ? BtQK : (BtVW - (size_t)1024 * 512);
  const float* bias = (n0 < 1024) ? biasQK : (biasVW - 1024);

  const int srow = lane >> 2;                              // staging row in 16-row chunk
  const int skg = ((lane & 3) ^ ((lane >> 3) & 3)) * 8;    // pre-swizzled global k-chunk
  const int fr = lane & 15;
  const int kq = (((lane >> 4) ^ ((lane >> 1) & 3)) & 3) * 8;  // swizzled read k-chunk

  f32x4 acc[4][4];
#pragma unroll
  for (int i = 0; i < 4; ++i)
#pragma unroll
    for (int j = 0; j < 4; ++j) acc[i][j] = (f32x4){0.f, 0.f, 0.f, 0.f};

  for (int kt = 0; kt < 512; kt += BK) {
    __syncthreads();
#pragma unroll
    for (int i = 0; i < 2; ++i) {
      int c = wave * 2 + i;
      int row = c * 16 + srow;
      gload_lds16(A + (size_t)(m0 + row) * 512 + kt + skg, &As[c * 16 * BK]);
      gload_lds16(Bt + (size_t)(n0 + row) * 512 + kt + skg, &Bs[c * 16 * BK]);
    }
    __syncthreads();

    bf16x8 af[4], bg[4];
#pragma unroll
    for (int i = 0; i < 4; ++i)
      af[i] = *(const bf16x8*)&As[(wr * 64 + i * 16 + fr) * BK + kq];
#pragma unroll
    for (int j = 0; j < 4; ++j)
      bg[j] = *(const bf16x8*)&Bs[(wc * 64 + j * 16 + fr) * BK + kq];
#pragma unroll
    for (int i = 0; i < 4; ++i)
#pragma unroll
      for (int j = 0; j < 4; ++j)
        acc[i][j] = __builtin_amdgcn_mfma_f32_16x16x32_bf16(af[i], bg[j], acc[i][j], 0, 0, 0);
  }

  // C/D layout: col=lane&15, row=(lane>>4)*4+reg  [m89/m91 verified]
#pragma unroll
  for (int i = 0; i < 4; ++i) {
    int grow0 = m0 + wr * 64 + i * 16 + (lane >> 4) * 4;
#pragma unroll
    for (int j = 0; j < 4; ++j) {
      int gcol = n0 + wc * 64 + j * 16 + fr;
      float bvv = bias[gcol];
#pragma unroll
      for (int q = 0; q < 4; ++q)
        out[(size_t)(grow0 + q) * 1536 + gcol] = (bf16)(acc[i][j][q] + bvv);
    }
  }
}

// ---------------- sparse masked attention + hop epilogue ---------------------
// QKW rows: Q at +0, K at +512, VW at +1024, ld=1536. One wave per (n,b) row.
// Epilogue: x[r] += relu(mix + b_hop);  xb[r] = bf16(x[r])
__global__ __launch_bounds__(256)
void attn_mix(const bf16* __restrict__ QKW, float* __restrict__ x,
              bf16* __restrict__ xb, const float* __restrict__ bhop) {
  const int lane = threadIdx.x & 63;
  const int wid = blockIdx.x * 4 + (threadIdx.x >> 6);  // (l,b,g) ordering for K reuse
  const int l = wid >> 8;
  const int b = (wid >> 4) & 15;
  const int g = wid & 15;
  const int r = (((g << 6) | l) << 4) | b;

  bf16x8 qv = *(const bf16x8*)(QKW + (size_t)r * 1536 + lane * 8);
  float qf[8];
#pragma unroll
  for (int i = 0; i < 8; ++i) qf[i] = (float)qv[i];

  int rows[17];
#pragma unroll
  for (int j = 0; j < 16; ++j) rows[j] = (((j << 6) | l) << 4) | b;
  rows[16] = (l < 63) ? (r + 16) : r;

  float s[17];
#pragma unroll
  for (int j = 0; j < 17; ++j) {
    const bf16* Krow = QKW + (size_t)rows[j] * 1536 + 512;
    bf16x8 kv = *(const bf16x8*)(Krow + lane * 8);
    float p = 0.f;
#pragma unroll
    for (int i = 0; i < 8; ++i) p += qf[i] * (float)kv[i];
#pragma unroll
    for (int off = 32; off; off >>= 1) p += __shfl_xor(p, off);
    p *= 0.044194173824159216f;  // 1/sqrt(512)
    bool valid = (j < 16) ? (j != g) : (l < 63);
    s[j] = valid ? p : -1e30f;
  }

  float mx = -1e30f;
#pragma unroll
  for (int j = 0; j < 17; ++j) mx = fmaxf(mx, s[j]);
  float pr[17], sum = 0.f;
#pragma unroll
  for (int j = 0; j < 17; ++j) { pr[j] = __expf(s[j] - mx); sum += pr[j]; }
  float inv = 1.f / sum;

  float acc[8] = {0, 0, 0, 0, 0, 0, 0, 0};
#pragma unroll
  for (int j = 0; j < 17; ++j) {
    const bf16* Vrow = QKW + (size_t)rows[j] * 1536 + 1024;
    bf16x8 vv = *(const bf16x8*)(Vrow + lane * 8);
    float w = pr[j] * inv;
#pragma unroll
    for (int i = 0; i < 8; ++i) acc[i] += w * (float)vv[i];
  }

  // epilogue: residual + relu + bf16 shadow
  const int d0 = lane * 8;
  size_t idx = (size_t)r * 512 + d0;
  float4 x0 = *(const float4*)(x + idx);
  float4 x1 = *(const float4*)(x + idx + 4);
  float4 bh0 = *(const float4*)(bhop + d0);
  float4 bh1 = *(const float4*)(bhop + d0 + 4);
  float xn[8];
  xn[0] = x0.x + fmaxf(acc[0] + bh0.x, 0.f);
  xn[1] = x0.y + fmaxf(acc[1] + bh0.y, 0.f);
  xn[2] = x0.z + fmaxf(acc[2] + bh0.z, 0.f);
  xn[3] = x0.w + fmaxf(acc[3] + bh0.w, 0.f);
  xn[4] = x1.x + fmaxf(acc[4] + bh1.x, 0.f);
  xn[5] = x1.y + fmaxf(acc[5] + bh1.y, 0.f);
  xn[6] = x1.z + fmaxf(acc[6] + bh1.z, 0.f);
  xn[7] = x1.w + fmaxf(acc[7] + bh1.w, 0.f);
  *(float4*)(x + idx)     = (float4){xn[0], xn[1], xn[2], xn[3]};
  *(float4*)(x + idx + 4) = (float4){xn[4], xn[5], xn[6], xn[7]};
  bf16x8 ov;
#pragma unroll
  for (int i = 0; i < 8; ++i) ov[i] = (bf16)xn[i];
  *(bf16x8*)(xb + idx) = ov;
}

// ---------------- mean over nodes + final MLP --------------------------------
__global__ void mean_partial(const float* __restrict__ x, float* __restrict__ partial) {
  int b = blockIdx.x, c = blockIdx.y, d = threadIdx.x;
  float s = 0.f;
#pragma unroll 4
  for (int n = c * 32; n < (c + 1) * 32; ++n)
    s += x[((size_t)(n * 16 + b)) * 512 + d];
  partial[(c * 16 + b) * 512 + d] = s;
}

__global__ void mean_final(const float* __restrict__ partial, float* __restrict__ agg) {
  int i = blockIdx.x * 256 + threadIdx.x;  // 8192
  float s = 0.f;
#pragma unroll
  for (int c = 0; c < 32; ++c) s += partial[c * 8192 + i];
  agg[i] = s * (1.0f / 1024.0f);
}

__global__ __launch_bounds__(256)
void mlp1(const float* __restrict__ agg, const float* __restrict__ W1t,
          const float* __restrict__ b1, float* __restrict__ hdn) {
  const int lane = threadIdx.x & 63;
  const int o = blockIdx.x * 4 + (threadIdx.x >> 6);   // 256 blocks * 4 waves
  const int b = lane & 15, q = lane >> 4;
  const float4* wp = (const float4*)(W1t + (size_t)o * 512 + q * 128);
  const float4* ap = (const float4*)(agg + b * 512 + q * 128);
  float acc = 0.f;
#pragma unroll
  for (int i = 0; i < 32; ++i) {
    float4 w = wp[i], a = ap[i];
    acc += w.x * a.x + w.y * a.y + w.z * a.z + w.w * a.w;
  }
  acc += __shfl_xor(acc, 16);
  acc += __shfl_xor(acc, 32);
  if (lane < 16) hdn[b * 1024 + o] = fmaxf(acc + b1[o], 0.f);
}

__global__ __launch_bounds__(256)
void mlp2(const float* __restrict__ hdn, const float* __restrict__ W2t,
          const float* __restrict__ b2, float* __restrict__ out) {
  const int lane = threadIdx.x & 63;
  const int o = blockIdx.x * 4 + (threadIdx.x >> 6);   // 128 blocks * 4 waves
  const int b = lane & 15, q = lane >> 4;
  const float4* wp = (const float4*)(W2t + (size_t)o * 1024 + q * 256);
  const float4* hp = (const float4*)(hdn + b * 1024 + q * 256);
  float acc = 0.f;
#pragma unroll
  for (int i = 0; i < 64; ++i) {
    float4 w = wp[i], h = hp[i];
    acc += w.x * h.x + w.y * h.y + w.z * h.z + w.w * h.w;
  }
  acc += __shfl_xor(acc, 16);
  acc += __shfl_xor(acc, 32);
  if (lane < 16) out[b * 512 + o] = acc + b2[o];
}

// ---------------- launch -----------------------------------------------------
extern "C" void kernel_launch(void* const* d_in, const int* in_sizes, int n_in,
                              void* d_out, int out_size, void* d_ws, size_t ws_size,
                              hipStream_t stream) {
  const float* what   = (const float*)d_in[0];
  const float* action = (const float*)d_in[1];
  const float* result = (const float*)d_in[2];
  const float* Wq = (const float*)d_in[3];
  const float* bq = (const float*)d_in[4];
  const float* Wk = (const float*)d_in[5];
  const float* bk = (const float*)d_in[6];
  const float* Wv = (const float*)d_in[7];
  const float* bv = (const float*)d_in[8];
  const float* Whop = (const float*)d_in[9];
  const float* bhop = (const float*)d_in[10];
  const float* W1 = (const float*)d_in[11];
  const float* b1 = (const float*)d_in[12];
  const float* W2 = (const float*)d_in[13];
  const float* b2 = (const float*)d_in[14];
  float* out = (float*)d_out;

  char* ws = (char*)d_ws;
  float* x      = (float*)(ws + 0);              // 33,554,432 B
  bf16*  xb     = (bf16*)(ws + 33554432);        // 16,777,216 B
  bf16*  QKW    = (bf16*)(ws + 50331648);        // 50,331,648 B (ld=1536)
  bf16*  WtQK   = (bf16*)(ws + 100663296);       //  1,048,576 B
  bf16*  WvwT   = (bf16*)(ws + 101711872);       //  1,572,864 B (3 hops)
  float* bcat   = (float*)(ws + 103284736);      //      4,096 B
  float* bvw    = (float*)(ws + 103288832);      //      6,144 B (3 hops)
  float* W1t    = (float*)(ws + 103294976);      //  2,097,152 B
  float* W2t    = (float*)(ws + 105392128);      //  2,097,152 B
  float* partial= (float*)(ws + 107489280);      //  1,048,576 B
  float* agg    = (float*)(ws + 108537856);      //     32,768 B
  float* hdn    = (float*)(ws + 108570624);      //     65,536 B

  prep_weights<<<6154, 256, 0, stream>>>(Wq, Wk, bq, bk, bv, Whop, W1, W2,
                                         WtQK, bcat, bvw, W1t, W2t);
  wvw_kernel<<<192, 256, 0, stream>>>(Wv, Whop, WvwT);
  nodes_kernel<<<2048, 256, 0, stream>>>((const float4*)what, (const float4*)action,
                                         (const float4*)result, (float4*)x, (bf16x4*)xb);
  for (int h = 0; h < 3; ++h) {
    gemm_qkw<<<dim3(128, 12), 256, 0, stream>>>(xb, WtQK, WvwT + h * 262144,
                                                bcat, bvw + h * 512, QKW);
    attn_mix<<<4096, 256, 0, stream>>>(QKW, x, xb, bhop + h * 512);
  }
  mean_partial<<<dim3(16, 32), 512, 0, stream>>>(x, partial);
  mean_final<<<32, 256, 0, stream>>>(partial, agg);
  mlp1<<<256, 256, 0, stream>>>(agg, W1t, b1, hdn);
  mlp2<<<128, 256, 0, stream>>>(hdn, W2t, b2, out);
}

// Round 4
// 329.712 us; speedup vs baseline: 1.1592x; 1.1592x over previous
//
#include <hip/hip_runtime.h>
#include <stdint.h>

// DreamGraphReasoner on MI355X (gfx950)
// x layout: (N, B, D) row-major, row r = n*B + b  (== input (G,L,B,D) flat order)
// Sparse attention: node n=(g,l) attends to {(g',l): g'!=g} U {(g,l+1) if l<63}
// Fusion: attended@Whop = attn@(V@Whop)  =>  QKV GEMM emits Q|K|VW_h directly,
// attn kernel mixes VW rows and applies residual+relu epilogue. No hop GEMM.
// Wvw = Wv@Whop computed by MFMA GEMM from bf16 operands (prepped, QKW-aliased).

typedef __bf16 bf16;
typedef __bf16 bf16x8 __attribute__((ext_vector_type(8)));
typedef __bf16 bf16x4 __attribute__((ext_vector_type(4)));
typedef float  f32x4  __attribute__((ext_vector_type(4)));

__device__ __forceinline__ void gload_lds16(const void* g, void* l) {
  __builtin_amdgcn_global_load_lds(
      (__attribute__((address_space(1))) void*)(size_t)(g),
      (__attribute__((address_space(3))) void*)(l), 16, 0, 0);
}

// ---------------- weight prep (coalesced reads; scattered writes L2-combine) --
__global__ void prep_weights(const float* __restrict__ Wq, const float* __restrict__ Wk,
                             const float* __restrict__ bq, const float* __restrict__ bk,
                             const float* __restrict__ Wv, const float* __restrict__ Whop,
                             const float* __restrict__ W1, const float* __restrict__ W2,
                             bf16* __restrict__ WtQK, float* __restrict__ bcat,
                             bf16* __restrict__ WhopTb, bf16* __restrict__ Wvb,
                             float* __restrict__ W1t, float* __restrict__ W2t) {
  int t = blockIdx.x * 256 + threadIdx.x;
  if (t < 524288) {                        // WtQK[sel*512+c][k] = W[k][c]
    int sel = t >> 18, k = (t >> 9) & 511, c = t & 511;
    const float* W = sel ? Wk : Wq;
    WtQK[(size_t)(sel * 512 + c) * 512 + k] = (bf16)W[k * 512 + c];
  } else if (t < 1048576) {                // W1t[o][d] = W1[d][o]
    int u = t - 524288;
    int d = u >> 10, o = u & 1023;
    W1t[(size_t)o * 512 + d] = W1[d * 1024 + o];
  } else if (t < 1572864) {                // W2t[o][d] = W2[d][o]
    int u = t - 1048576;
    int d = u >> 9, o = u & 511;
    W2t[(size_t)o * 1024 + d] = W2[d * 512 + o];
  } else if (t < 1573888) {
    int u = t - 1572864;
    bcat[u] = (u < 512) ? bq[u] : bk[u - 512];
  } else if (t < 2360320) {                // WhopTb[h*512+c][d] = Whop[h][d][c]
    int u = t - 1573888;
    int h = u >> 18, rem = u & 262143;
    int d = rem >> 9, c = rem & 511;
    WhopTb[(size_t)h * 262144 + (size_t)c * 512 + d] = (bf16)Whop[h * 262144 + d * 512 + c];
  } else if (t < 2622464) {                // Wvb = bf16(Wv)
    int u = t - 2360320;
    Wvb[u] = (bf16)Wv[u];
  }
}

// ---------------- bvw[h][c] = sum_d bv[d] * Whop[h][d][c]  (wave per output) --
__global__ __launch_bounds__(256)
void bvw_kernel(const float* __restrict__ bv, const float* __restrict__ Whop,
                float* __restrict__ bvw) {
  int w = blockIdx.x * 4 + (threadIdx.x >> 6);  // 0..1535
  int lane = threadIdx.x & 63;
  int h = w >> 9, c = w & 511;
  int d0 = lane * 8;
  const float* wh = Whop + h * 262144 + c;
  float p = 0.f;
#pragma unroll
  for (int i = 0; i < 8; ++i) p += bv[d0 + i] * wh[(d0 + i) * 512];
#pragma unroll
  for (int off = 32; off; off >>= 1) p += __shfl_xor(p, off);
  if (lane == 0) bvw[w] = p;
}

// ---------------- node embeddings: x = mean(what,action,result) --------------
__global__ void nodes_kernel(const float4* __restrict__ w, const float4* __restrict__ a,
                             const float4* __restrict__ r, float4* __restrict__ x,
                             bf16x4* __restrict__ xb) {
  size_t i = (size_t)blockIdx.x * 256 + threadIdx.x;
#pragma unroll
  for (int it = 0; it < 4; ++it, i += 524288) {
    float4 vw = w[i], va = a[i], vr = r[i];
    float4 v;
    v.x = (vw.x + va.x + vr.x) * (1.f / 3.f);
    v.y = (vw.y + va.y + vr.y) * (1.f / 3.f);
    v.z = (vw.z + va.z + vr.z) * (1.f / 3.f);
    v.w = (vw.w + va.w + vr.w) * (1.f / 3.f);
    x[i] = v;
    bf16x4 bv4;
    bv4[0] = (bf16)v.x; bv4[1] = (bf16)v.y; bv4[2] = (bf16)v.z; bv4[3] = (bf16)v.w;
    xb[i] = bv4;
  }
}

// ---------------- plain bf16 MFMA GEMM: out(1536x512) = A @ Bt^T -------------
// A = WhopTb (1536x512), Bt = Wvb (512x512), out = WvwT[h*512+c][k], ld 512
__global__ __launch_bounds__(256)
void gemm_plain(const bf16* __restrict__ A, const bf16* __restrict__ Bt,
                bf16* __restrict__ out) {
  constexpr int BK = 32;
  __shared__ __align__(16) bf16 As[128 * BK];
  __shared__ __align__(16) bf16 Bs[128 * BK];
  const int tid = threadIdx.x;
  const int wave = tid >> 6, lane = tid & 63;
  const int wr = wave >> 1, wc = wave & 1;
  const int m0 = blockIdx.x * 128;
  const int n0 = blockIdx.y * 128;
  const int srow = lane >> 2;
  const int skg = ((lane & 3) ^ ((lane >> 3) & 3)) * 8;
  const int fr = lane & 15;
  const int kq = (((lane >> 4) ^ ((lane >> 1) & 3)) & 3) * 8;

  f32x4 acc[4][4];
#pragma unroll
  for (int i = 0; i < 4; ++i)
#pragma unroll
    for (int j = 0; j < 4; ++j) acc[i][j] = (f32x4){0.f, 0.f, 0.f, 0.f};

  for (int kt = 0; kt < 512; kt += BK) {
    __syncthreads();
#pragma unroll
    for (int i = 0; i < 2; ++i) {
      int c = wave * 2 + i;
      int row = c * 16 + srow;
      gload_lds16(A + (size_t)(m0 + row) * 512 + kt + skg, &As[c * 16 * BK]);
      gload_lds16(Bt + (size_t)(n0 + row) * 512 + kt + skg, &Bs[c * 16 * BK]);
    }
    __syncthreads();

    bf16x8 af[4], bg[4];
#pragma unroll
    for (int i = 0; i < 4; ++i)
      af[i] = *(const bf16x8*)&As[(wr * 64 + i * 16 + fr) * BK + kq];
#pragma unroll
    for (int j = 0; j < 4; ++j)
      bg[j] = *(const bf16x8*)&Bs[(wc * 64 + j * 16 + fr) * BK + kq];
#pragma unroll
    for (int i = 0; i < 4; ++i)
#pragma unroll
      for (int j = 0; j < 4; ++j)
        acc[i][j] = __builtin_amdgcn_mfma_f32_16x16x32_bf16(af[i], bg[j], acc[i][j], 0, 0, 0);
  }

#pragma unroll
  for (int i = 0; i < 4; ++i) {
    int grow0 = m0 + wr * 64 + i * 16 + (lane >> 4) * 4;
#pragma unroll
    for (int j = 0; j < 4; ++j) {
      int gcol = n0 + wc * 64 + j * 16 + fr;
#pragma unroll
      for (int q = 0; q < 4; ++q)
        out[(size_t)(grow0 + q) * 512 + gcol] = (bf16)acc[i][j][q];
    }
  }
}

// ---------------- bf16 MFMA GEMM: QKW = A(16384x512) @ [WqT|WkT|WvwT]^T + bias
__global__ __launch_bounds__(256)
void gemm_qkw(const bf16* __restrict__ A, const bf16* __restrict__ BtQK,
              const bf16* __restrict__ BtVW, const float* __restrict__ biasQK,
              const float* __restrict__ biasVW, bf16* __restrict__ out) {
  constexpr int BK = 32;
  __shared__ __align__(16) bf16 As[128 * BK];
  __shared__ __align__(16) bf16 Bs[128 * BK];
  const int tid = threadIdx.x;
  const int wave = tid >> 6, lane = tid & 63;
  const int wr = wave >> 1, wc = wave & 1;
  const int m0 = blockIdx.x * 128;
  const int n0 = blockIdx.y * 128;
  const bf16* Bt = (n0 < 1024) ? BtQK : (BtVW - (size_t)1024 * 512);
  const float* bias = (n0 < 1024) ? biasQK : (biasVW - 1024);

  const int srow = lane >> 2;
  const int skg = ((lane & 3) ^ ((lane >> 3) & 3)) * 8;
  const int fr = lane & 15;
  const int kq = (((lane >> 4) ^ ((lane >> 1) & 3)) & 3) * 8;

  f32x4 acc[4][4];
#pragma unroll
  for (int i = 0; i < 4; ++i)
#pragma unroll
    for (int j = 0; j < 4; ++j) acc[i][j] = (f32x4){0.f, 0.f, 0.f, 0.f};

  for (int kt = 0; kt < 512; kt += BK) {
    __syncthreads();
#pragma unroll
    for (int i = 0; i < 2; ++i) {
      int c = wave * 2 + i;
      int row = c * 16 + srow;
      gload_lds16(A + (size_t)(m0 + row) * 512 + kt + skg, &As[c * 16 * BK]);
      gload_lds16(Bt + (size_t)(n0 + row) * 512 + kt + skg, &Bs[c * 16 * BK]);
    }
    __syncthreads();

    bf16x8 af[4], bg[4];
#pragma unroll
    for (int i = 0; i < 4; ++i)
      af[i] = *(const bf16x8*)&As[(wr * 64 + i * 16 + fr) * BK + kq];
#pragma unroll
    for (int j = 0; j < 4; ++j)
      bg[j] = *(const bf16x8*)&Bs[(wc * 64 + j * 16 + fr) * BK + kq];
#pragma unroll
    for (int i = 0; i < 4; ++i)
#pragma unroll
      for (int j = 0; j < 4; ++j)
        acc[i][j] = __builtin_amdgcn_mfma_f32_16x16x32_bf16(af[i], bg[j], acc[i][j], 0, 0, 0);
  }

#pragma unroll
  for (int i = 0; i < 4; ++i) {
    int grow0 = m0 + wr * 64 + i * 16 + (lane >> 4) * 4;
#pragma unroll
    for (int j = 0; j < 4; ++j) {
      int gcol = n0 + wc * 64 + j * 16 + fr;
      float bvv = bias[gcol];
#pragma unroll
      for (int q = 0; q < 4; ++q)
        out[(size_t)(grow0 + q) * 1536 + gcol] = (bf16)(acc[i][j][q] + bvv);
    }
  }
}

// ---------------- sparse masked attention + hop epilogue ---------------------
// 512-thread blocks: 8 waves = 8 dreams per (l,b) -> K/VW rows shared via L1
__global__ __launch_bounds__(512)
void attn_mix(const bf16* __restrict__ QKW, float* __restrict__ x,
              bf16* __restrict__ xb, const float* __restrict__ bhop) {
  const int tid = threadIdx.x;
  const int lane = tid & 63;
  const int l = blockIdx.x >> 5;
  const int b = (blockIdx.x >> 1) & 15;
  const int g = ((blockIdx.x & 1) << 3) | (tid >> 6);
  const int r = (((g << 6) | l) << 4) | b;

  bf16x8 qv = *(const bf16x8*)(QKW + (size_t)r * 1536 + lane * 8);
  float qf[8];
#pragma unroll
  for (int i = 0; i < 8; ++i) qf[i] = (float)qv[i];

  int rows[17];
#pragma unroll
  for (int j = 0; j < 16; ++j) rows[j] = (((j << 6) | l) << 4) | b;
  rows[16] = (l < 63) ? (r + 16) : r;

  float s[17];
#pragma unroll
  for (int j = 0; j < 17; ++j) {
    const bf16* Krow = QKW + (size_t)rows[j] * 1536 + 512;
    bf16x8 kv = *(const bf16x8*)(Krow + lane * 8);
    float p = 0.f;
#pragma unroll
    for (int i = 0; i < 8; ++i) p += qf[i] * (float)kv[i];
#pragma unroll
    for (int off = 32; off; off >>= 1) p += __shfl_xor(p, off);
    p *= 0.044194173824159216f;  // 1/sqrt(512)
    bool valid = (j < 16) ? (j != g) : (l < 63);
    s[j] = valid ? p : -1e30f;
  }

  float mx = -1e30f;
#pragma unroll
  for (int j = 0; j < 17; ++j) mx = fmaxf(mx, s[j]);
  float pr[17], sum = 0.f;
#pragma unroll
  for (int j = 0; j < 17; ++j) { pr[j] = __expf(s[j] - mx); sum += pr[j]; }
  float inv = 1.f / sum;

  float acc[8] = {0, 0, 0, 0, 0, 0, 0, 0};
#pragma unroll
  for (int j = 0; j < 17; ++j) {
    const bf16* Vrow = QKW + (size_t)rows[j] * 1536 + 1024;
    bf16x8 vv = *(const bf16x8*)(Vrow + lane * 8);
    float w = pr[j] * inv;
#pragma unroll
    for (int i = 0; i < 8; ++i) acc[i] += w * (float)vv[i];
  }

  const int d0 = lane * 8;
  size_t idx = (size_t)r * 512 + d0;
  float4 x0 = *(const float4*)(x + idx);
  float4 x1 = *(const float4*)(x + idx + 4);
  float4 bh0 = *(const float4*)(bhop + d0);
  float4 bh1 = *(const float4*)(bhop + d0 + 4);
  float xn[8];
  xn[0] = x0.x + fmaxf(acc[0] + bh0.x, 0.f);
  xn[1] = x0.y + fmaxf(acc[1] + bh0.y, 0.f);
  xn[2] = x0.z + fmaxf(acc[2] + bh0.z, 0.f);
  xn[3] = x0.w + fmaxf(acc[3] + bh0.w, 0.f);
  xn[4] = x1.x + fmaxf(acc[4] + bh1.x, 0.f);
  xn[5] = x1.y + fmaxf(acc[5] + bh1.y, 0.f);
  xn[6] = x1.z + fmaxf(acc[6] + bh1.z, 0.f);
  xn[7] = x1.w + fmaxf(acc[7] + bh1.w, 0.f);
  *(float4*)(x + idx)     = (float4){xn[0], xn[1], xn[2], xn[3]};
  *(float4*)(x + idx + 4) = (float4){xn[4], xn[5], xn[6], xn[7]};
  bf16x8 ov;
#pragma unroll
  for (int i = 0; i < 8; ++i) ov[i] = (bf16)xn[i];
  *(bf16x8*)(xb + idx) = ov;
}

// ---------------- mean over nodes + final MLP --------------------------------
__global__ void mean_partial(const float* __restrict__ x, float* __restrict__ partial) {
  int b = blockIdx.x, c = blockIdx.y, d = threadIdx.x;
  float s = 0.f;
#pragma unroll 4
  for (int n = c * 32; n < (c + 1) * 32; ++n)
    s += x[((size_t)(n * 16 + b)) * 512 + d];
  partial[(c * 16 + b) * 512 + d] = s;
}

__global__ void mean_final(const float* __restrict__ partial, float* __restrict__ agg) {
  int i = blockIdx.x * 256 + threadIdx.x;  // 8192
  float s = 0.f;
#pragma unroll
  for (int c = 0; c < 32; ++c) s += partial[c * 8192 + i];
  agg[i] = s * (1.0f / 1024.0f);
}

__global__ __launch_bounds__(256)
void mlp1(const float* __restrict__ agg, const float* __restrict__ W1t,
          const float* __restrict__ b1, float* __restrict__ hdn) {
  const int lane = threadIdx.x & 63;
  const int o = blockIdx.x * 4 + (threadIdx.x >> 6);
  const int b = lane & 15, q = lane >> 4;
  const float4* wp = (const float4*)(W1t + (size_t)o * 512 + q * 128);
  const float4* ap = (const float4*)(agg + b * 512 + q * 128);
  float acc = 0.f;
#pragma unroll
  for (int i = 0; i < 32; ++i) {
    float4 w = wp[i], a = ap[i];
    acc += w.x * a.x + w.y * a.y + w.z * a.z + w.w * a.w;
  }
  acc += __shfl_xor(acc, 16);
  acc += __shfl_xor(acc, 32);
  if (lane < 16) hdn[b * 1024 + o] = fmaxf(acc + b1[o], 0.f);
}

__global__ __launch_bounds__(256)
void mlp2(const float* __restrict__ hdn, const float* __restrict__ W2t,
          const float* __restrict__ b2, float* __restrict__ out) {
  const int lane = threadIdx.x & 63;
  const int o = blockIdx.x * 4 + (threadIdx.x >> 6);
  const int b = lane & 15, q = lane >> 4;
  const float4* wp = (const float4*)(W2t + (size_t)o * 1024 + q * 256);
  const float4* hp = (const float4*)(hdn + b * 1024 + q * 256);
  float acc = 0.f;
#pragma unroll
  for (int i = 0; i < 64; ++i) {
    float4 w = wp[i], h = hp[i];
    acc += w.x * h.x + w.y * h.y + w.z * h.z + w.w * h.w;
  }
  acc += __shfl_xor(acc, 16);
  acc += __shfl_xor(acc, 32);
  if (lane < 16) out[b * 512 + o] = acc + b2[o];
}

// ---------------- launch -----------------------------------------------------
extern "C" void kernel_launch(void* const* d_in, const int* in_sizes, int n_in,
                              void* d_out, int out_size, void* d_ws, size_t ws_size,
                              hipStream_t stream) {
  const float* what   = (const float*)d_in[0];
  const float* action = (const float*)d_in[1];
  const float* result = (const float*)d_in[2];
  const float* Wq = (const float*)d_in[3];
  const float* bq = (const float*)d_in[4];
  const float* Wk = (const float*)d_in[5];
  const float* bk = (const float*)d_in[6];
  const float* Wv = (const float*)d_in[7];
  const float* bv = (const float*)d_in[8];
  const float* Whop = (const float*)d_in[9];
  const float* bhop = (const float*)d_in[10];
  const float* W1 = (const float*)d_in[11];
  const float* b1 = (const float*)d_in[12];
  const float* W2 = (const float*)d_in[13];
  const float* b2 = (const float*)d_in[14];
  float* out = (float*)d_out;

  char* ws = (char*)d_ws;
  float* x      = (float*)(ws + 0);              // 33,554,432 B
  bf16*  xb     = (bf16*)(ws + 33554432);        // 16,777,216 B
  bf16*  QKW    = (bf16*)(ws + 50331648);        // 50,331,648 B (ld=1536)
  // WhopTb/Wvb alias the QKW region: consumed by gemm_plain before hop 0 writes QKW
  bf16*  WhopTb = (bf16*)(ws + 50331648);        //  1,572,864 B (alias)
  bf16*  Wvb    = (bf16*)(ws + 51904512);        //    524,288 B (alias)
  bf16*  WtQK   = (bf16*)(ws + 100663296);       //  1,048,576 B
  bf16*  WvwT   = (bf16*)(ws + 101711872);       //  1,572,864 B (3 hops)
  float* bcat   = (float*)(ws + 103284736);      //      4,096 B
  float* bvw    = (float*)(ws + 103288832);      //      6,144 B (3 hops)
  float* W1t    = (float*)(ws + 103294976);      //  2,097,152 B
  float* W2t    = (float*)(ws + 105392128);      //  2,097,152 B
  float* partial= (float*)(ws + 107489280);      //  1,048,576 B
  float* agg    = (float*)(ws + 108537856);      //     32,768 B
  float* hdn    = (float*)(ws + 108570624);      //     65,536 B

  prep_weights<<<10244, 256, 0, stream>>>(Wq, Wk, bq, bk, Wv, Whop, W1, W2,
                                          WtQK, bcat, WhopTb, Wvb, W1t, W2t);
  bvw_kernel<<<384, 256, 0, stream>>>(bv, Whop, bvw);
  gemm_plain<<<dim3(12, 4), 256, 0, stream>>>(WhopTb, Wvb, WvwT);
  nodes_kernel<<<2048, 256, 0, stream>>>((const float4*)what, (const float4*)action,
                                         (const float4*)result, (float4*)x, (bf16x4*)xb);
  for (int h = 0; h < 3; ++h) {
    gemm_qkw<<<dim3(128, 12), 256, 0, stream>>>(xb, WtQK, WvwT + h * 262144,
                                                bcat, bvw + h * 512, QKW);
    attn_mix<<<2048, 512, 0, stream>>>(QKW, x, xb, bhop + h * 512);
  }
  mean_partial<<<dim3(16, 32), 512, 0, stream>>>(x, partial);
  mean_final<<<32, 256, 0, stream>>>(partial, agg);
  mlp1<<<256, 256, 0, stream>>>(agg, W1t, b1, hdn);
  mlp2<<<128, 256, 0, stream>>>(hdn, W2t, b2, out);
}